// Round 6
// baseline (177.851 us; speedup 1.0000x reference)
//
#include <hip/hip_runtime.h>
#include <math.h>

// D = 8192, BATCH = 4096
// out[b, j] = x[b] * w_col[j]
// w_col[j]  = s1[0] * s2[j] * FWHT(g_tilde)[j]
// g_tilde[i] = g_mu[i] + softplus(g_rho[i]) * epsilon[i]
//
// Round 6 — DIAGNOSTIC (single-variable): identical to round 5 except
// whvi_stream is launched TWICE (second launch overwrites the same values;
// output bit-identical, serialized on stream). In every timing model,
// dur_us(round6) - dur_us(round5=158.0) == t_stream, the true duration of
// the streaming kernel, which the top-5 profile view cannot show (all five
// slots are 80 us harness poison fills). Decision rule committed in journal:
// delta 18-32 us => streamer at write floor, harness-dominated => ROOFLINE;
// delta 45-85 us => streamer capped ~2 TB/s => real headroom, attack store
// path next round.

#define WHVI_D 8192
#define WHVI_BATCH 4096

typedef float v4f __attribute__((ext_vector_type(4)));

// ---------------- Kernel A: compute w into workspace (1 block) -------------
__global__ __launch_bounds__(1024) void whvi_make_w(
    const float* __restrict__ s1, const float* __restrict__ s2,
    const float* __restrict__ g_mu, const float* __restrict__ g_rho,
    const float* __restrict__ eps, float* __restrict__ w) {
  __shared__ float s[WHVI_D];
  const int tid = threadIdx.x;

  // g_tilde = g_mu + softplus(g_rho)*eps, then FWHT stages h=1,2 in-register
  const float4* mu4 = (const float4*)g_mu;
  const float4* rh4 = (const float4*)g_rho;
  const float4* ep4 = (const float4*)eps;
  #pragma unroll
  for (int t = 0; t < 2; ++t) {
    int i = tid + t * 1024;
    float4 m = mu4[i], r = rh4[i], e = ep4[i];
    float g0 = m.x + (fmaxf(r.x, 0.0f) + log1pf(expf(-fabsf(r.x)))) * e.x;
    float g1 = m.y + (fmaxf(r.y, 0.0f) + log1pf(expf(-fabsf(r.y)))) * e.y;
    float g2 = m.z + (fmaxf(r.z, 0.0f) + log1pf(expf(-fabsf(r.z)))) * e.z;
    float g3 = m.w + (fmaxf(r.w, 0.0f) + log1pf(expf(-fabsf(r.w)))) * e.w;
    // stage h=1: pairs (0,1) (2,3)
    float b0 = g0 + g1, b1 = g0 - g1, b2 = g2 + g3, b3 = g2 - g3;
    // stage h=2: pairs (0,2) (1,3)
    float4 o;
    o.x = b0 + b2; o.y = b1 + b3; o.z = b0 - b2; o.w = b1 - b3;
    ((float4*)s)[i] = o;
  }

  // Remaining 11 stages (h = 4 .. 4096) in LDS. Worst aliasing 2-way (free).
  for (int h = 4; h < WHVI_D; h <<= 1) {
    __syncthreads();
    #pragma unroll
    for (int t = 0; t < 4; ++t) {
      int p = tid + t * 1024;           // 4096 butterflies, 4 per thread
      int k = p & (h - 1);
      int i = ((p - k) << 1) + k;       // (p/h)*2h + k
      float a = s[i];
      float b = s[i + h];
      s[i]     = a + b;
      s[i + h] = a - b;
    }
  }
  __syncthreads();

  // w = s1[0] * s2 * fwht(g_tilde) — plain stores so kernel B hits L2/L3.
  const float s10 = s1[0];
  const v4f* s24 = (const v4f*)s2;
  const v4f* sh4 = (const v4f*)s;
  ((v4f*)w)[tid]        = (s10 * s24[tid])        * sh4[tid];
  ((v4f*)w)[tid + 1024] = (s10 * s24[tid + 1024]) * sh4[tid + 1024];
}

// ---------------- Kernel B: fill-clone streaming broadcast -----------------
// 2048 blocks x 256 threads, 2 rows/block. Per row: thread t stores
// o4[t + k*256] (k=0..7) — each wave instruction covers 1 KB contiguous,
// 8 instructions cover the row's 32 KB. Plain cached stores.
#define STREAM_TPB 256
#define STREAM_ROWS 2
#define STREAM_BLOCKS (WHVI_BATCH / STREAM_ROWS)   // 2048

__global__ __launch_bounds__(STREAM_TPB) void whvi_stream(
    const float* __restrict__ x, const float* __restrict__ w,
    float* __restrict__ out) {
  const int t = threadIdx.x;
  const v4f* w4 = (const v4f*)w;

  v4f wf[8];
  #pragma unroll
  for (int k = 0; k < 8; ++k) wf[k] = w4[t + k * STREAM_TPB];

  const int row0 = blockIdx.x * STREAM_ROWS;
  #pragma unroll
  for (int r = 0; r < STREAM_ROWS; ++r) {
    const int row = row0 + r;
    const float xb = x[row];
    v4f* o4 = (v4f*)(out + (size_t)row * WHVI_D);
    #pragma unroll
    for (int k = 0; k < 8; ++k)
      o4[t + k * STREAM_TPB] = xb * wf[k];
  }
}

extern "C" void kernel_launch(void* const* d_in, const int* in_sizes, int n_in,
                              void* d_out, int out_size, void* d_ws, size_t ws_size,
                              hipStream_t stream) {
  const float* x     = (const float*)d_in[0];  // (4096,1)
  const float* s1    = (const float*)d_in[1];  // (8192,)
  const float* s2    = (const float*)d_in[2];  // (8192,)
  const float* g_mu  = (const float*)d_in[3];  // (8192,)
  const float* g_rho = (const float*)d_in[4];  // (8192,)
  const float* eps   = (const float*)d_in[5];  // (8192,)
  float* out = (float*)d_out;                  // (4096, 8192)
  float* w   = (float*)d_ws;                   // 32 KB scratch for w_col

  whvi_make_w<<<1, 1024, 0, stream>>>(s1, s2, g_mu, g_rho, eps, w);
  // DIAGNOSTIC double-launch: identical writes twice; delta vs round 5
  // directly measures t_stream. Remove after the measurement round.
  whvi_stream<<<STREAM_BLOCKS, STREAM_TPB, 0, stream>>>(x, w, out);
  whvi_stream<<<STREAM_BLOCKS, STREAM_TPB, 0, stream>>>(x, w, out);
}

// Round 7
// 156.269 us; speedup vs baseline: 1.1381x; 1.1381x over previous
//
#include <hip/hip_runtime.h>
#include <math.h>

// D = 8192, BATCH = 4096
// out[b, j] = x[b] * w_col[j]
// w_col[j]  = s1[0] * s2[j] * FWHT(g_tilde)[j]
// g_tilde[i] = g_mu[i] + softplus(g_rho[i]) * epsilon[i]
//
// Round 7 — restore round-5 kernel (diagnostic double-launch removed).
// Round-6 measurement: t_stream = 177.85 - 158.04 = 19.8 us for 134.2 MB
// => 6.78 TB/s, at/above the harness fill's own 6.5 TB/s on the same buffer.
// Controllable GPU work is ~24 us (make_w ~4 + stream ~20); the remaining
// ~134 us of dur_us is harness-constant (512 MiB poison fills dominate the
// top-5 profile). The streaming phase is AT the write floor — no headroom.

#define WHVI_D 8192
#define WHVI_BATCH 4096

typedef float v4f __attribute__((ext_vector_type(4)));

// ---------------- Kernel A: compute w into workspace (1 block) -------------
__global__ __launch_bounds__(1024) void whvi_make_w(
    const float* __restrict__ s1, const float* __restrict__ s2,
    const float* __restrict__ g_mu, const float* __restrict__ g_rho,
    const float* __restrict__ eps, float* __restrict__ w) {
  __shared__ float s[WHVI_D];
  const int tid = threadIdx.x;

  // g_tilde = g_mu + softplus(g_rho)*eps, then FWHT stages h=1,2 in-register
  const float4* mu4 = (const float4*)g_mu;
  const float4* rh4 = (const float4*)g_rho;
  const float4* ep4 = (const float4*)eps;
  #pragma unroll
  for (int t = 0; t < 2; ++t) {
    int i = tid + t * 1024;
    float4 m = mu4[i], r = rh4[i], e = ep4[i];
    float g0 = m.x + (fmaxf(r.x, 0.0f) + log1pf(expf(-fabsf(r.x)))) * e.x;
    float g1 = m.y + (fmaxf(r.y, 0.0f) + log1pf(expf(-fabsf(r.y)))) * e.y;
    float g2 = m.z + (fmaxf(r.z, 0.0f) + log1pf(expf(-fabsf(r.z)))) * e.z;
    float g3 = m.w + (fmaxf(r.w, 0.0f) + log1pf(expf(-fabsf(r.w)))) * e.w;
    // stage h=1: pairs (0,1) (2,3)
    float b0 = g0 + g1, b1 = g0 - g1, b2 = g2 + g3, b3 = g2 - g3;
    // stage h=2: pairs (0,2) (1,3)
    float4 o;
    o.x = b0 + b2; o.y = b1 + b3; o.z = b0 - b2; o.w = b1 - b3;
    ((float4*)s)[i] = o;
  }

  // Remaining 11 stages (h = 4 .. 4096) in LDS. Worst aliasing 2-way (free).
  for (int h = 4; h < WHVI_D; h <<= 1) {
    __syncthreads();
    #pragma unroll
    for (int t = 0; t < 4; ++t) {
      int p = tid + t * 1024;           // 4096 butterflies, 4 per thread
      int k = p & (h - 1);
      int i = ((p - k) << 1) + k;       // (p/h)*2h + k
      float a = s[i];
      float b = s[i + h];
      s[i]     = a + b;
      s[i + h] = a - b;
    }
  }
  __syncthreads();

  // w = s1[0] * s2 * fwht(g_tilde) — plain stores so kernel B hits L2/L3.
  const float s10 = s1[0];
  const v4f* s24 = (const v4f*)s2;
  const v4f* sh4 = (const v4f*)s;
  ((v4f*)w)[tid]        = (s10 * s24[tid])        * sh4[tid];
  ((v4f*)w)[tid + 1024] = (s10 * s24[tid + 1024]) * sh4[tid + 1024];
}

// ---------------- Kernel B: fill-clone streaming broadcast -----------------
// 2048 blocks x 256 threads, 2 rows/block. Per row: thread t stores
// o4[t + k*256] (k=0..7) — each wave instruction covers 1 KB contiguous,
// 8 instructions cover the row's 32 KB. Plain cached stores.
// Measured (round-6 double-launch delta): 19.8 us for 134.2 MB = 6.78 TB/s.
#define STREAM_TPB 256
#define STREAM_ROWS 2
#define STREAM_BLOCKS (WHVI_BATCH / STREAM_ROWS)   // 2048

__global__ __launch_bounds__(STREAM_TPB) void whvi_stream(
    const float* __restrict__ x, const float* __restrict__ w,
    float* __restrict__ out) {
  const int t = threadIdx.x;
  const v4f* w4 = (const v4f*)w;

  v4f wf[8];
  #pragma unroll
  for (int k = 0; k < 8; ++k) wf[k] = w4[t + k * STREAM_TPB];

  const int row0 = blockIdx.x * STREAM_ROWS;
  #pragma unroll
  for (int r = 0; r < STREAM_ROWS; ++r) {
    const int row = row0 + r;
    const float xb = x[row];
    v4f* o4 = (v4f*)(out + (size_t)row * WHVI_D);
    #pragma unroll
    for (int k = 0; k < 8; ++k)
      o4[t + k * STREAM_TPB] = xb * wf[k];
  }
}

extern "C" void kernel_launch(void* const* d_in, const int* in_sizes, int n_in,
                              void* d_out, int out_size, void* d_ws, size_t ws_size,
                              hipStream_t stream) {
  const float* x     = (const float*)d_in[0];  // (4096,1)
  const float* s1    = (const float*)d_in[1];  // (8192,)
  const float* s2    = (const float*)d_in[2];  // (8192,)
  const float* g_mu  = (const float*)d_in[3];  // (8192,)
  const float* g_rho = (const float*)d_in[4];  // (8192,)
  const float* eps   = (const float*)d_in[5];  // (8192,)
  float* out = (float*)d_out;                  // (4096, 8192)
  float* w   = (float*)d_ws;                   // 32 KB scratch for w_col

  whvi_make_w<<<1, 1024, 0, stream>>>(s1, s2, g_mu, g_rho, eps, w);
  whvi_stream<<<STREAM_BLOCKS, STREAM_TPB, 0, stream>>>(x, w, out);
}